// Round 1
// baseline (559.535 us; speedup 1.0000x reference)
//
#include <hip/hip_runtime.h>
#include <hip/hip_bf16.h>
#include <math.h>

#define BB 8
#define NN 200000
#define CC 81
#define TOPK 200
#define EQCAP 512

// ---------------------------------------------------------------------------
// Kernel A: scores[p] = 1 / sum_c exp(logits[p,c] - max_c logits[p,c])
// (== max over classes of softmax, since exp(0)=1 is the max unnormalized term
//  and float division is monotone)
// 16-lane groups per proposal: coalesced 64B reads, shfl reductions.
// ---------------------------------------------------------------------------
__global__ __launch_bounds__(256) void scores_kernel(const float* __restrict__ logits,
                                                     float* __restrict__ scores,
                                                     int total) {
    int gtid = blockIdx.x * blockDim.x + threadIdx.x;
    int wave = gtid >> 6;
    int lane = threadIdx.x & 63;
    int group = lane >> 4;
    int sub = lane & 15;
    int p = wave * 4 + group;
    if (p >= total) return;
    const float* row = logits + (size_t)p * CC;

    float m = -INFINITY;
#pragma unroll
    for (int j = 0; j < 6; ++j) {
        int c = sub + j * 16;
        if (c < CC) m = fmaxf(m, row[c]);
    }
#pragma unroll
    for (int w = 1; w < 16; w <<= 1) m = fmaxf(m, __shfl_xor(m, w, 64));

    float ss = 0.0f;
#pragma unroll
    for (int j = 0; j < 6; ++j) {
        int c = sub + j * 16;
        if (c < CC) ss += expf(row[c] - m);
    }
#pragma unroll
    for (int w = 1; w < 16; w <<= 1) ss += __shfl_xor(ss, w, 64);

    if (sub == 0) scores[p] = 1.0f / ss;
}

// ---------------------------------------------------------------------------
// Kernel B: per-batch exact top-200 (radix select on float bits, stable-sort
// boundary tie rule: largest indices win) + greedy NMS (argmax tie -> smallest
// original index), early exit, zero padding. One block per batch.
// ---------------------------------------------------------------------------
__global__ __launch_bounds__(1024) void select_nms_kernel(const float* __restrict__ scores,
                                                          const float* __restrict__ segs,
                                                          int* __restrict__ out) {
    int b = blockIdx.x;
    const float* sc = scores + (size_t)b * NN;
    const float* sg = segs + (size_t)b * NN * 2;

    __shared__ unsigned hist[256];
    __shared__ unsigned s_prefix;
    __shared__ int s_K;
    __shared__ int s_ngt, s_neq;
    __shared__ float cs[TOPK], cx1[TOPK], cx2[TOPK];
    __shared__ int cidx[TOPK];
    __shared__ int eq_idx[EQCAP];

    int tid = threadIdx.x;
    if (tid == 0) { s_prefix = 0u; s_K = TOPK; s_ngt = 0; s_neq = 0; }

    // ---- radix select: 4 levels x 8 bits, descending rank K=200 ----
    for (int l = 0; l < 4; ++l) {
        if (tid < 256) hist[tid] = 0u;
        __syncthreads();
        unsigned prefix = s_prefix;
        int shift_lo = 24 - 8 * l;
        for (int i = tid; i < NN; i += 1024) {
            unsigned key = __float_as_uint(sc[i]);  // all scores > 0 -> bit order == value order
            bool ok = (l == 0) || ((key >> (shift_lo + 8)) == prefix);
            if (ok) atomicAdd(&hist[(key >> shift_lo) & 255u], 1u);
        }
        __syncthreads();
        if (tid == 0) {
            int K = s_K;
            unsigned cum = 0, before = 0;
            int sel = 0;
            for (int bin = 255; bin >= 0; --bin) {
                unsigned c = hist[bin];
                if (cum + c >= (unsigned)K) { sel = bin; before = cum; break; }
                cum += c;
            }
            s_prefix = (prefix << 8) | (unsigned)sel;
            s_K = K - (int)before;
        }
        __syncthreads();
    }
    unsigned T = s_prefix;  // exact 200th-largest key; s_K = #to take among == T

    // ---- gather: all keys > T, plus list of keys == T ----
    for (int i = tid; i < NN; i += 1024) {
        unsigned key = __float_as_uint(sc[i]);
        if (key > T) {
            int pos = atomicAdd(&s_ngt, 1);
            cidx[pos] = i;                       // pos <= 198 guaranteed (s_K >= 1)
        } else if (key == T) {
            int pos = atomicAdd(&s_neq, 1);
            if (pos < EQCAP) eq_idx[pos] = i;
        }
    }
    __syncthreads();

    // boundary ties: stable ascending argsort keeps LARGEST indices among ==T
    if (tid == 0) {
        int ngt = s_ngt;
        int take = TOPK - ngt;
        int ne = s_neq; if (ne > EQCAP) ne = EQCAP;
        for (int t = 0; t < take; ++t) {
            int bi = 0, bv = -1;
            for (int j = 0; j < ne; ++j) {
                int v = eq_idx[j];
                if (v > bv) { bv = v; bi = j; }
            }
            cidx[ngt + t] = bv;
            eq_idx[bi] = -1;
        }
    }
    __syncthreads();

    if (tid < TOPK) {
        int i = cidx[tid];
        cs[tid] = sc[i];
        cx1[tid] = sg[2 * (size_t)i];
        cx2[tid] = sg[2 * (size_t)i + 1];
    }
    // zero mirror rows 8..15 while we're at it
    for (int i = tid; i < TOPK; i += 1024) out[(BB + b) * TOPK + i] = 0;
    __syncthreads();

    // ---- greedy NMS on wave 0 only; candidates in registers (4 slots/lane) ----
    if (tid >= 64) return;
    int lane = tid;
    float rs[4], rx1[4], rx2[4];
    int ridx[4];
    bool act[4];
#pragma unroll
    for (int k = 0; k < 4; ++k) {
        int c = k * 64 + lane;
        if (c < TOPK) {
            rs[k] = cs[c]; rx1[k] = cx1[c]; rx2[k] = cx2[c];
            ridx[k] = cidx[c]; act[k] = true;
        } else {
            rs[k] = -INFINITY; rx1[k] = 0.f; rx2[k] = 0.f;
            ridx[k] = 0x7fffffff; act[k] = false;
        }
    }

    int* keep = out + b * TOPK;
    int it = 0;
    for (; it < TOPK; ++it) {
        // local argmax (score desc, original index asc)
        float bs = -INFINITY; int bidx = 0x7fffffff; float bx1 = 0.f, bx2 = 0.f;
#pragma unroll
        for (int k = 0; k < 4; ++k) {
            if (act[k] && (rs[k] > bs || (rs[k] == bs && ridx[k] < bidx))) {
                bs = rs[k]; bidx = ridx[k]; bx1 = rx1[k]; bx2 = rx2[k];
            }
        }
        // wave butterfly reduce carrying (s, idx, x1, x2)
#pragma unroll
        for (int w = 1; w < 64; w <<= 1) {
            float os  = __shfl_xor(bs, w, 64);
            int   oix = __shfl_xor(bidx, w, 64);
            float ox1 = __shfl_xor(bx1, w, 64);
            float ox2 = __shfl_xor(bx2, w, 64);
            if (os > bs || (os == bs && oix < bidx)) { bs = os; bidx = oix; bx1 = ox1; bx2 = ox2; }
        }
        if (bs == -INFINITY) break;  // no active left -> rest of kept are 0
        if (lane == 0) keep[it] = bidx;
        // suppress winner + positive-overlap boxes (OVERLAP = 0.0)
#pragma unroll
        for (int k = 0; k < 4; ++k) {
            if (act[k]) {
                if (ridx[k] == bidx) act[k] = false;
                else {
                    float inter = fminf(rx2[k], bx2) - fmaxf(rx1[k], bx1);
                    if (inter > 0.f) act[k] = false;
                }
            }
        }
    }
    for (int j = it + lane; j < TOPK; j += 64) keep[j] = 0;
}

extern "C" void kernel_launch(void* const* d_in, const int* in_sizes, int n_in,
                              void* d_out, int out_size, void* d_ws, size_t ws_size,
                              hipStream_t stream) {
    const float* logits = (const float*)d_in[0];   // (8, 200000, 81) f32
    const float* segs   = (const float*)d_in[1];   // (8, 200000, 2)  f32
    int* out = (int*)d_out;                        // (16, 200) int32
    float* scores = (float*)d_ws;                  // 8*200000 f32 = 6.4 MB scratch

    int total = BB * NN;                           // 1.6M proposals
    int waves = (total + 3) / 4;                   // 4 proposals per wave
    int blocks = (waves * 64 + 255) / 256;

    scores_kernel<<<blocks, 256, 0, stream>>>(logits, scores, total);
    select_nms_kernel<<<BB, 1024, 0, stream>>>(scores, segs, out);
}

// Round 2
// 293.447 us; speedup vs baseline: 1.9068x; 1.9068x over previous
//
#include <hip/hip_runtime.h>
#include <hip/hip_bf16.h>
#include <math.h>

#define BB 8
#define NN 200000
#define CC 81
#define TOPK 200
#define CAP 4096
#define NBIN 4096

static __device__ __forceinline__ int bin_of(unsigned key) {
    // score in [1/81, 1] -> exponent in [120,127]; bits above bit 25 constant.
    // 12-bit monotone bin: exp low-3 bits + top-9 mantissa bits.
    return (int)((key >> 14) & (NBIN - 1));
}

// ---------------------------------------------------------------------------
// Kernel A: scores[p] = 1 / sum_c exp(logits[p,c] - max_c logits[p,c])
// ---------------------------------------------------------------------------
__global__ __launch_bounds__(256) void scores_kernel(const float* __restrict__ logits,
                                                     float* __restrict__ scores,
                                                     int total) {
    int gtid = blockIdx.x * blockDim.x + threadIdx.x;
    int wave = gtid >> 6;
    int lane = threadIdx.x & 63;
    int group = lane >> 4;
    int sub = lane & 15;
    int p = wave * 4 + group;
    if (p >= total) return;
    const float* row = logits + (size_t)p * CC;

    float m = -INFINITY;
#pragma unroll
    for (int j = 0; j < 6; ++j) {
        int c = sub + j * 16;
        if (c < CC) m = fmaxf(m, row[c]);
    }
#pragma unroll
    for (int w = 1; w < 16; w <<= 1) m = fmaxf(m, __shfl_xor(m, w, 64));

    float ss = 0.0f;
#pragma unroll
    for (int j = 0; j < 6; ++j) {
        int c = sub + j * 16;
        if (c < CC) ss += expf(row[c] - m);
    }
#pragma unroll
    for (int w = 1; w < 16; w <<= 1) ss += __shfl_xor(ss, w, 64);

    if (sub == 0) scores[p] = 1.0f / ss;
}

// ---------------------------------------------------------------------------
// Kernel B: per-batch 4096-bin histogram, many blocks (grid = (chunks, batch))
// ---------------------------------------------------------------------------
__global__ __launch_bounds__(256) void hist_kernel(const float* __restrict__ scores,
                                                   unsigned* __restrict__ hist) {
    __shared__ unsigned h[NBIN];
    int tid = threadIdx.x;
    int b = blockIdx.y;
    for (int i = tid; i < NBIN; i += 256) h[i] = 0u;
    __syncthreads();

    int per = (NN + gridDim.x - 1) / gridDim.x;
    int start = blockIdx.x * per;
    int end = min(start + per, NN);
    const float* sc = scores + (size_t)b * NN;
    for (int i = start + tid; i < end; i += 256) {
        unsigned key = __float_as_uint(sc[i]);
        atomicAdd(&h[bin_of(key)], 1u);
    }
    __syncthreads();
    unsigned* gh = hist + (size_t)b * NBIN;
    for (int i = tid; i < NBIN; i += 256) {
        unsigned c = h[i];
        if (c) atomicAdd(&gh[i], c);
    }
}

// ---------------------------------------------------------------------------
// Kernel C: per-batch threshold bin = highest bin where cumulative (from top)
// count >= TOPK. One block per batch.
// ---------------------------------------------------------------------------
__global__ __launch_bounds__(256) void thresh_kernel(const unsigned* __restrict__ hist,
                                                     int* __restrict__ thresh) {
    __shared__ unsigned csum[256];
    int tid = threadIdx.x;
    int b = blockIdx.x;
    const unsigned* gh = hist + (size_t)b * NBIN;
    // chunk t covers bins [hi-15 .. hi] with hi = 4095 - 16*t (descending order)
    int hi = NBIN - 1 - 16 * tid;
    unsigned s = 0;
#pragma unroll
    for (int j = 0; j < 16; ++j) s += gh[hi - j];
    csum[tid] = s;
    __syncthreads();
    if (tid == 0) {
        unsigned run = 0;
        for (int t = 0; t < 256; ++t) { unsigned tmp = csum[t]; csum[t] = run; run += tmp; }
    }
    __syncthreads();
    unsigned before = csum[tid];
    if (before < TOPK && before + s >= TOPK) {
        unsigned cum = before;
        for (int j = 0; j < 16; ++j) {
            cum += gh[hi - j];
            if (cum >= TOPK) { thresh[b] = hi - j; break; }
        }
    }
}

// ---------------------------------------------------------------------------
// Kernel D: compact candidate indices (bin >= thresh) per batch
// ---------------------------------------------------------------------------
__global__ __launch_bounds__(256) void compact_kernel(const float* __restrict__ scores,
                                                      const int* __restrict__ thresh,
                                                      int* __restrict__ cand,
                                                      int* __restrict__ cnt) {
    int b = blockIdx.y;
    int t = thresh[b];
    const float* sc = scores + (size_t)b * NN;
    for (int i = blockIdx.x * 256 + threadIdx.x; i < NN; i += gridDim.x * 256) {
        unsigned key = __float_as_uint(sc[i]);
        if (bin_of(key) >= t) {
            int pos = atomicAdd(&cnt[b], 1);
            if (pos < CAP) cand[(size_t)b * CAP + pos] = i;
        }
    }
}

// ---------------------------------------------------------------------------
// Kernel E: exact top-200 by (key desc, idx desc) rank among candidates
// (== stable ascending argsort, take last 200), then greedy NMS
// (argmax tie -> smallest index), early exit, zero padding. 1 block/batch.
// ---------------------------------------------------------------------------
__global__ __launch_bounds__(1024) void final_kernel(const float* __restrict__ scores,
                                                     const float* __restrict__ segs,
                                                     const int* __restrict__ cand,
                                                     const int* __restrict__ cnt,
                                                     int* __restrict__ out) {
    __shared__ unsigned k_key[CAP];
    __shared__ int k_idx[CAP];
    __shared__ float sel_s[TOPK], sel_x1[TOPK], sel_x2[TOPK];
    __shared__ int sel_i[TOPK];

    int b = blockIdx.x;
    int tid = threadIdx.x;
    const float* sc = scores + (size_t)b * NN;
    const float* sg = segs + (size_t)b * NN * 2;
    int M = cnt[b]; if (M > CAP) M = CAP;

    for (int j = tid; j < M; j += 1024) {
        int idx = cand[(size_t)b * CAP + j];
        k_idx[j] = idx;
        k_key[j] = __float_as_uint(sc[idx]);
    }
    // zero mirror rows 8..15
    for (int i = tid; i < TOPK; i += 1024) out[(BB + b) * TOPK + i] = 0;
    __syncthreads();

    for (int j = tid; j < M; j += 1024) {
        unsigned kj = k_key[j];
        int ij = k_idx[j];
        int rank = 0;
        for (int m = 0; m < M; ++m) {
            unsigned km = k_key[m];
            rank += (km > kj) || (km == kj && k_idx[m] > ij);
        }
        if (rank < TOPK) {
            sel_s[rank] = __uint_as_float(kj);
            sel_i[rank] = ij;
            sel_x1[rank] = sg[2 * (size_t)ij];
            sel_x2[rank] = sg[2 * (size_t)ij + 1];
        }
    }
    __syncthreads();

    if (tid >= 64) return;
    int lane = tid;
    float rs[4], rx1[4], rx2[4];
    int ridx[4];
    bool act[4];
#pragma unroll
    for (int k = 0; k < 4; ++k) {
        int c = k * 64 + lane;
        if (c < TOPK) {
            rs[k] = sel_s[c]; rx1[k] = sel_x1[c]; rx2[k] = sel_x2[c];
            ridx[k] = sel_i[c]; act[k] = true;
        } else {
            rs[k] = -INFINITY; rx1[k] = 0.f; rx2[k] = 0.f;
            ridx[k] = 0x7fffffff; act[k] = false;
        }
    }

    int* keep = out + b * TOPK;
    int it = 0;
    for (; it < TOPK; ++it) {
        float bs = -INFINITY; int bidx = 0x7fffffff; float bx1 = 0.f, bx2 = 0.f;
#pragma unroll
        for (int k = 0; k < 4; ++k) {
            if (act[k] && (rs[k] > bs || (rs[k] == bs && ridx[k] < bidx))) {
                bs = rs[k]; bidx = ridx[k]; bx1 = rx1[k]; bx2 = rx2[k];
            }
        }
#pragma unroll
        for (int w = 1; w < 64; w <<= 1) {
            float os  = __shfl_xor(bs, w, 64);
            int   oix = __shfl_xor(bidx, w, 64);
            float ox1 = __shfl_xor(bx1, w, 64);
            float ox2 = __shfl_xor(bx2, w, 64);
            if (os > bs || (os == bs && oix < bidx)) { bs = os; bidx = oix; bx1 = ox1; bx2 = ox2; }
        }
        if (bs == -INFINITY) break;
        if (lane == 0) keep[it] = bidx;
#pragma unroll
        for (int k = 0; k < 4; ++k) {
            if (act[k]) {
                if (ridx[k] == bidx) act[k] = false;
                else {
                    float inter = fminf(rx2[k], bx2) - fmaxf(rx1[k], bx1);
                    if (inter > 0.f) act[k] = false;
                }
            }
        }
    }
    for (int j = it + lane; j < TOPK; j += 64) keep[j] = 0;
}

extern "C" void kernel_launch(void* const* d_in, const int* in_sizes, int n_in,
                              void* d_out, int out_size, void* d_ws, size_t ws_size,
                              hipStream_t stream) {
    const float* logits = (const float*)d_in[0];   // (8, 200000, 81) f32
    const float* segs   = (const float*)d_in[1];   // (8, 200000, 2)  f32
    int* out = (int*)d_out;                        // (16, 200) int32

    // ws layout
    char* ws = (char*)d_ws;
    float*    scores = (float*)ws;                                  // 6,400,000 B
    unsigned* hist   = (unsigned*)(ws + 6400000);                   // 131,072 B
    int*      cnt    = (int*)(ws + 6400000 + 131072);               // 32 B
    int*      thresh = (int*)(ws + 6400000 + 131072 + 32);          // 32 B
    int*      cand   = (int*)(ws + 6400000 + 131072 + 64);          // 131,072 B

    hipMemsetAsync(ws + 6400000, 0, 131072 + 32, stream);           // hist + cnt

    int total = BB * NN;
    int waves = (total + 3) / 4;
    int blocks = (waves * 64 + 255) / 256;
    scores_kernel<<<blocks, 256, 0, stream>>>(logits, scores, total);

    dim3 hgrid(64, BB);
    hist_kernel<<<hgrid, 256, 0, stream>>>(scores, hist);
    thresh_kernel<<<BB, 256, 0, stream>>>(hist, thresh);
    dim3 cgrid(128, BB);
    compact_kernel<<<cgrid, 256, 0, stream>>>(scores, thresh, cand, cnt);
    final_kernel<<<BB, 1024, 0, stream>>>(scores, segs, cand, cnt, out);
}

// Round 3
// 293.131 us; speedup vs baseline: 1.9088x; 1.0011x over previous
//
#include <hip/hip_runtime.h>
#include <hip/hip_bf16.h>
#include <math.h>

#define BB 8
#define NN 200000
#define CC 81
#define TOPK 200
#define CAP 4096
#define NBIN 4096

static __device__ __forceinline__ int bin_of(unsigned key) {
    // score in [1/81, 1] -> exponent in [120,127]; bits above bit 25 constant.
    // 12-bit monotone bin: exp low-3 bits + top-9 mantissa bits.
    return (int)((key >> 14) & (NBIN - 1));
}

// ---------------------------------------------------------------------------
// Kernel Z: zero hist (BB*NBIN words) + cnt (BB words). Replaces the
// pathologically slow rocclr fill blit (~313us profiled for 131KB).
// ---------------------------------------------------------------------------
__global__ __launch_bounds__(256) void zero_kernel(unsigned* __restrict__ hist_and_cnt,
                                                   int nwords) {
    int i = blockIdx.x * 256 + threadIdx.x;
    if (i < nwords) hist_and_cnt[i] = 0u;
}

// ---------------------------------------------------------------------------
// Kernel A: scores[p] = 1 / sum_c exp(logits[p,c] - max_c logits[p,c])
// ---------------------------------------------------------------------------
__global__ __launch_bounds__(256) void scores_kernel(const float* __restrict__ logits,
                                                     float* __restrict__ scores,
                                                     int total) {
    int gtid = blockIdx.x * blockDim.x + threadIdx.x;
    int wave = gtid >> 6;
    int lane = threadIdx.x & 63;
    int group = lane >> 4;
    int sub = lane & 15;
    int p = wave * 4 + group;
    if (p >= total) return;
    const float* row = logits + (size_t)p * CC;

    float m = -INFINITY;
#pragma unroll
    for (int j = 0; j < 6; ++j) {
        int c = sub + j * 16;
        if (c < CC) m = fmaxf(m, row[c]);
    }
#pragma unroll
    for (int w = 1; w < 16; w <<= 1) m = fmaxf(m, __shfl_xor(m, w, 64));

    float ss = 0.0f;
#pragma unroll
    for (int j = 0; j < 6; ++j) {
        int c = sub + j * 16;
        if (c < CC) ss += expf(row[c] - m);
    }
#pragma unroll
    for (int w = 1; w < 16; w <<= 1) ss += __shfl_xor(ss, w, 64);

    if (sub == 0) scores[p] = 1.0f / ss;
}

// ---------------------------------------------------------------------------
// Kernel B: per-batch 4096-bin histogram, many blocks (grid = (chunks, batch))
// ---------------------------------------------------------------------------
__global__ __launch_bounds__(256) void hist_kernel(const float* __restrict__ scores,
                                                   unsigned* __restrict__ hist) {
    __shared__ unsigned h[NBIN];
    int tid = threadIdx.x;
    int b = blockIdx.y;
    for (int i = tid; i < NBIN; i += 256) h[i] = 0u;
    __syncthreads();

    int per = (NN + gridDim.x - 1) / gridDim.x;
    int start = blockIdx.x * per;
    int end = min(start + per, NN);
    const float* sc = scores + (size_t)b * NN;
    for (int i = start + tid; i < end; i += 256) {
        unsigned key = __float_as_uint(sc[i]);
        atomicAdd(&h[bin_of(key)], 1u);
    }
    __syncthreads();
    unsigned* gh = hist + (size_t)b * NBIN;
    for (int i = tid; i < NBIN; i += 256) {
        unsigned c = h[i];
        if (c) atomicAdd(&gh[i], c);
    }
}

// ---------------------------------------------------------------------------
// Kernel C: per-batch threshold bin = highest bin where cumulative (from top)
// count >= TOPK. One block per batch.
// ---------------------------------------------------------------------------
__global__ __launch_bounds__(256) void thresh_kernel(const unsigned* __restrict__ hist,
                                                     int* __restrict__ thresh) {
    __shared__ unsigned csum[256];
    int tid = threadIdx.x;
    int b = blockIdx.x;
    const unsigned* gh = hist + (size_t)b * NBIN;
    // chunk t covers bins [hi-15 .. hi] with hi = 4095 - 16*t (descending order)
    int hi = NBIN - 1 - 16 * tid;
    unsigned s = 0;
#pragma unroll
    for (int j = 0; j < 16; ++j) s += gh[hi - j];
    csum[tid] = s;
    __syncthreads();
    if (tid == 0) {
        unsigned run = 0;
        for (int t = 0; t < 256; ++t) { unsigned tmp = csum[t]; csum[t] = run; run += tmp; }
    }
    __syncthreads();
    unsigned before = csum[tid];
    if (before < TOPK && before + s >= TOPK) {
        unsigned cum = before;
        for (int j = 0; j < 16; ++j) {
            cum += gh[hi - j];
            if (cum >= TOPK) { thresh[b] = hi - j; break; }
        }
    }
}

// ---------------------------------------------------------------------------
// Kernel D: compact candidate indices (bin >= thresh) per batch
// ---------------------------------------------------------------------------
__global__ __launch_bounds__(256) void compact_kernel(const float* __restrict__ scores,
                                                      const int* __restrict__ thresh,
                                                      int* __restrict__ cand,
                                                      int* __restrict__ cnt) {
    int b = blockIdx.y;
    int t = thresh[b];
    const float* sc = scores + (size_t)b * NN;
    for (int i = blockIdx.x * 256 + threadIdx.x; i < NN; i += gridDim.x * 256) {
        unsigned key = __float_as_uint(sc[i]);
        if (bin_of(key) >= t) {
            int pos = atomicAdd(&cnt[b], 1);
            if (pos < CAP) cand[(size_t)b * CAP + pos] = i;
        }
    }
}

// ---------------------------------------------------------------------------
// Kernel E: exact top-200 by (key desc, idx desc) rank among candidates
// (== stable ascending argsort, take last 200), then greedy NMS
// (argmax tie -> smallest index), early exit, zero padding. 1 block/batch.
// ---------------------------------------------------------------------------
__global__ __launch_bounds__(1024) void final_kernel(const float* __restrict__ scores,
                                                     const float* __restrict__ segs,
                                                     const int* __restrict__ cand,
                                                     const int* __restrict__ cnt,
                                                     int* __restrict__ out) {
    __shared__ unsigned k_key[CAP];
    __shared__ int k_idx[CAP];
    __shared__ float sel_s[TOPK], sel_x1[TOPK], sel_x2[TOPK];
    __shared__ int sel_i[TOPK];

    int b = blockIdx.x;
    int tid = threadIdx.x;
    const float* sc = scores + (size_t)b * NN;
    const float* sg = segs + (size_t)b * NN * 2;
    int M = cnt[b]; if (M > CAP) M = CAP;

    for (int j = tid; j < M; j += 1024) {
        int idx = cand[(size_t)b * CAP + j];
        k_idx[j] = idx;
        k_key[j] = __float_as_uint(sc[idx]);
    }
    // zero mirror rows 8..15
    for (int i = tid; i < TOPK; i += 1024) out[(BB + b) * TOPK + i] = 0;
    __syncthreads();

    for (int j = tid; j < M; j += 1024) {
        unsigned kj = k_key[j];
        int ij = k_idx[j];
        int rank = 0;
        for (int m = 0; m < M; ++m) {
            unsigned km = k_key[m];
            rank += (km > kj) || (km == kj && k_idx[m] > ij);
        }
        if (rank < TOPK) {
            sel_s[rank] = __uint_as_float(kj);
            sel_i[rank] = ij;
            sel_x1[rank] = sg[2 * (size_t)ij];
            sel_x2[rank] = sg[2 * (size_t)ij + 1];
        }
    }
    __syncthreads();

    if (tid >= 64) return;
    int lane = tid;
    float rs[4], rx1[4], rx2[4];
    int ridx[4];
    bool act[4];
#pragma unroll
    for (int k = 0; k < 4; ++k) {
        int c = k * 64 + lane;
        if (c < TOPK) {
            rs[k] = sel_s[c]; rx1[k] = sel_x1[c]; rx2[k] = sel_x2[c];
            ridx[k] = sel_i[c]; act[k] = true;
        } else {
            rs[k] = -INFINITY; rx1[k] = 0.f; rx2[k] = 0.f;
            ridx[k] = 0x7fffffff; act[k] = false;
        }
    }

    int* keep = out + b * TOPK;
    int it = 0;
    for (; it < TOPK; ++it) {
        float bs = -INFINITY; int bidx = 0x7fffffff; float bx1 = 0.f, bx2 = 0.f;
#pragma unroll
        for (int k = 0; k < 4; ++k) {
            if (act[k] && (rs[k] > bs || (rs[k] == bs && ridx[k] < bidx))) {
                bs = rs[k]; bidx = ridx[k]; bx1 = rx1[k]; bx2 = rx2[k];
            }
        }
#pragma unroll
        for (int w = 1; w < 64; w <<= 1) {
            float os  = __shfl_xor(bs, w, 64);
            int   oix = __shfl_xor(bidx, w, 64);
            float ox1 = __shfl_xor(bx1, w, 64);
            float ox2 = __shfl_xor(bx2, w, 64);
            if (os > bs || (os == bs && oix < bidx)) { bs = os; bidx = oix; bx1 = ox1; bx2 = ox2; }
        }
        if (bs == -INFINITY) break;
        if (lane == 0) keep[it] = bidx;
#pragma unroll
        for (int k = 0; k < 4; ++k) {
            if (act[k]) {
                if (ridx[k] == bidx) act[k] = false;
                else {
                    float inter = fminf(rx2[k], bx2) - fmaxf(rx1[k], bx1);
                    if (inter > 0.f) act[k] = false;
                }
            }
        }
    }
    for (int j = it + lane; j < TOPK; j += 64) keep[j] = 0;
}

extern "C" void kernel_launch(void* const* d_in, const int* in_sizes, int n_in,
                              void* d_out, int out_size, void* d_ws, size_t ws_size,
                              hipStream_t stream) {
    const float* logits = (const float*)d_in[0];   // (8, 200000, 81) f32
    const float* segs   = (const float*)d_in[1];   // (8, 200000, 2)  f32
    int* out = (int*)d_out;                        // (16, 200) int32

    // ws layout
    char* ws = (char*)d_ws;
    float*    scores = (float*)ws;                                  // 6,400,000 B
    unsigned* hist   = (unsigned*)(ws + 6400000);                   // 131,072 B
    int*      cnt    = (int*)(ws + 6400000 + 131072);               // 32 B
    int*      thresh = (int*)(ws + 6400000 + 131072 + 32);          // 32 B
    int*      cand   = (int*)(ws + 6400000 + 131072 + 64);          // 131,072 B

    // zero hist + cnt (contiguous: NBIN*BB + BB words)
    int nwords = NBIN * BB + BB;
    zero_kernel<<<(nwords + 255) / 256, 256, 0, stream>>>(hist, nwords);

    int total = BB * NN;
    int waves = (total + 3) / 4;
    int blocks = (waves * 64 + 255) / 256;
    scores_kernel<<<blocks, 256, 0, stream>>>(logits, scores, total);

    dim3 hgrid(64, BB);
    hist_kernel<<<hgrid, 256, 0, stream>>>(scores, hist);
    thresh_kernel<<<BB, 256, 0, stream>>>(hist, thresh);
    dim3 cgrid(128, BB);
    compact_kernel<<<cgrid, 256, 0, stream>>>(scores, thresh, cand, cnt);
    final_kernel<<<BB, 1024, 0, stream>>>(scores, segs, cand, cnt, out);
}